// Round 1
// baseline (1192.257 us; speedup 1.0000x reference)
//
#include <hip/hip_runtime.h>

// Two-hop SpMM-mean (biclique encoder).
// Hop1: bf[b,:]  = (1/deg_v[b]) * sum_{e: hv_rows[e]==b} hv_vals[e] * item_emb[hv_cols[e],:]
// Hop2: out[u,:] = (1/deg_u[u]) * sum_{e: hu_rows[e]==u} hu_vals[e] * bf[hu_cols[e],:]
// deg == 0 treated as 1 (matches reference).
//
// Round 1: atomic scatter baseline. One 64-lane wave per edge; lane d handles dim d.

#define DIM 64

__global__ void scatter_edges_kernel(const int* __restrict__ rows,
                                     const int* __restrict__ cols,
                                     const float* __restrict__ vals,
                                     const float* __restrict__ src,   // [n_src, 64]
                                     float* __restrict__ num,         // [n_dst, 64] (pre-zeroed)
                                     float* __restrict__ deg,         // [n_dst]     (pre-zeroed)
                                     int nnz) {
    long long tid = (long long)blockIdx.x * blockDim.x + threadIdx.x;
    int lane = (int)(tid & 63);
    long long e = tid >> 6;
    if (e >= (long long)nnz) return;
    int r = rows[e];
    int c = cols[e];
    float v = vals[e];
    float x = src[(long long)c * DIM + lane];
    atomicAdd(&num[(long long)r * DIM + lane], v * x);
    if (lane == 0) atomicAdd(&deg[r], v);
}

__global__ void divide_deg_kernel(float* __restrict__ num,   // [n, 64], in place
                                  const float* __restrict__ deg,  // [n]
                                  int n_elems) {                    // n * 64
    int i = blockIdx.x * blockDim.x + threadIdx.x;
    if (i >= n_elems) return;
    float d = deg[i >> 6];   // i / DIM
    d = (d == 0.0f) ? 1.0f : d;
    num[i] = num[i] / d;
}

extern "C" void kernel_launch(void* const* d_in, const int* in_sizes, int n_in,
                              void* d_out, int out_size, void* d_ws, size_t ws_size,
                              hipStream_t stream) {
    // Inputs (setup_inputs order):
    // 0: user_emb (unused), 1: item_emb, 2: hv_rows, 3: hv_cols, 4: hv_vals,
    // 5: hu_rows, 6: hu_cols, 7: hu_vals, 8: n_bicliques (dev scalar), 9: n_users (dev scalar)
    const float* item_emb = (const float*)d_in[1];
    const int*   hv_rows  = (const int*)d_in[2];
    const int*   hv_cols  = (const int*)d_in[3];
    const float* hv_vals  = (const float*)d_in[4];
    const int*   hu_rows  = (const int*)d_in[5];
    const int*   hu_cols  = (const int*)d_in[6];
    const float* hu_vals  = (const float*)d_in[7];

    const int nnz1 = in_sizes[2];
    const int nnz2 = in_sizes[5];
    const int n_b  = 50000;             // fixed by problem (device scalar not host-readable here)
    const int n_u  = out_size / DIM;

    float* out   = (float*)d_out;
    float* bf    = (float*)d_ws;                    // [n_b * 64] hop-1 numerator -> features
    float* deg_v = bf + (size_t)n_b * DIM;          // [n_b]
    float* deg_u = deg_v + n_b;                     // [n_u]

    // Zero accumulators (ws is poisoned 0xAA each call; memsetAsync is capture-safe).
    size_t ws_floats = (size_t)n_b * DIM + (size_t)n_b + (size_t)n_u;
    hipMemsetAsync(bf, 0, ws_floats * sizeof(float), stream);
    hipMemsetAsync(out, 0, (size_t)out_size * sizeof(float), stream);

    const int block = 256;

    // Hop 1: item_emb -> bf numerator
    {
        long long threads = (long long)nnz1 * 64;
        int grid = (int)((threads + block - 1) / block);
        scatter_edges_kernel<<<grid, block, 0, stream>>>(hv_rows, hv_cols, hv_vals,
                                                         item_emb, bf, deg_v, nnz1);
        int n_el = n_b * DIM;
        divide_deg_kernel<<<(n_el + block - 1) / block, block, 0, stream>>>(bf, deg_v, n_el);
    }

    // Hop 2: bf -> out numerator
    {
        long long threads = (long long)nnz2 * 64;
        int grid = (int)((threads + block - 1) / block);
        scatter_edges_kernel<<<grid, block, 0, stream>>>(hu_rows, hu_cols, hu_vals,
                                                         bf, out, deg_u, nnz2);
        int n_el = n_u * DIM;
        divide_deg_kernel<<<(n_el + block - 1) / block, block, 0, stream>>>(out, deg_u, n_el);
    }
}

// Round 2
// 820.823 us; speedup vs baseline: 1.4525x; 1.4525x over previous
//
#include <hip/hip_runtime.h>

// Two-hop SpMM-mean. Round 2: device-side CSR build + gather-side segmented
// reduction. No fp32 atomics; each output row written exactly once.
//
// Per hop:
//   1. histogram rows            (2M int atomics)
//   2. exclusive scan -> row_off (3-kernel scan)
//   3. scatter edges to sorted order (col_s, val_s)
//   4. gather: one wave per row; lane d owns dim d; edge cols broadcast
//      via __shfl; divide by degree fused at the store.

#define DIM 64

__global__ void hist_kernel(const int* __restrict__ rows, int nnz,
                            int* __restrict__ counts) {
    int i = blockIdx.x * blockDim.x + threadIdx.x;
    if (i < nnz) atomicAdd(&counts[rows[i]], 1);
}

// Per-block exclusive scan (block=256). Writes per-block-exclusive values and
// the block total.
__global__ void scan_blocks_kernel(const int* __restrict__ in, int n,
                                   int* __restrict__ out,
                                   int* __restrict__ block_sums) {
    __shared__ int s[256];
    int t = threadIdx.x;
    int i = blockIdx.x * 256 + t;
    int x = (i < n) ? in[i] : 0;
    s[t] = x;
    __syncthreads();
    // Hillis-Steele inclusive scan
    for (int off = 1; off < 256; off <<= 1) {
        int v = (t >= off) ? s[t - off] : 0;
        __syncthreads();
        s[t] += v;
        __syncthreads();
    }
    if (i < n) out[i] = s[t] - x;          // exclusive
    if (t == 255) block_sums[blockIdx.x] = s[255];
}

// Single-block exclusive scan of up to 512 block sums (in place).
__global__ void scan_sums_kernel(int* __restrict__ sums, int n) {
    __shared__ int s[512];
    int t = threadIdx.x;
    int x = (t < n) ? sums[t] : 0;
    s[t] = x;
    __syncthreads();
    for (int off = 1; off < 512; off <<= 1) {
        int v = (t >= off) ? s[t - off] : 0;
        __syncthreads();
        s[t] += v;
        __syncthreads();
    }
    if (t < n) sums[t] = s[t] - x;         // exclusive
}

__global__ void add_offsets_kernel(int* __restrict__ out,
                                   const int* __restrict__ sums, int n) {
    int i = blockIdx.x * 256 + threadIdx.x;
    if (i < n) out[i] += sums[blockIdx.x];
}

__global__ void scatter_sorted_kernel(const int* __restrict__ rows,
                                      const int* __restrict__ cols,
                                      const float* __restrict__ vals,
                                      const int* __restrict__ row_off,
                                      int* __restrict__ cursor,      // zeroed
                                      int* __restrict__ col_s,
                                      float* __restrict__ val_s,
                                      int nnz) {
    int i = blockIdx.x * blockDim.x + threadIdx.x;
    if (i >= nnz) return;
    int r = rows[i];
    int pos = row_off[r] + atomicAdd(&cursor[r], 1);
    col_s[pos] = cols[i];
    val_s[pos] = vals[i];
}

// One 64-lane wave per row; 4 waves per block. lane d accumulates dim d.
__global__ void gather_rows_kernel(const int* __restrict__ col_s,
                                   const float* __restrict__ val_s,
                                   const int* __restrict__ row_off,
                                   const float* __restrict__ src,   // [n_src,64]
                                   float* __restrict__ dst,         // [n_rows,64]
                                   int n_rows, int nnz) {
    int wave = (blockIdx.x * blockDim.x + threadIdx.x) >> 6;
    int lane = threadIdx.x & 63;
    if (wave >= n_rows) return;
    int start = row_off[wave];
    int end   = (wave + 1 < n_rows) ? row_off[wave + 1] : nnz;

    float acc = 0.0f;
    float vsum = 0.0f;
    for (int i = start; i < end; i += 64) {
        int idx = i + lane;
        int cnt = end - i; if (cnt > 64) cnt = 64;
        int   c = (idx < end) ? col_s[idx] : 0;
        float v = (idx < end) ? val_s[idx] : 0.0f;
        vsum += v;
        for (int j = 0; j < cnt; ++j) {
            int   cj = __shfl(c, j);
            float vj = __shfl(v, j);
            acc += vj * src[(long long)cj * DIM + lane];
        }
    }
    // wave-wide degree reduction (all lanes need it)
    for (int off = 32; off > 0; off >>= 1) vsum += __shfl_xor(vsum, off);
    float d = (vsum == 0.0f) ? 1.0f : vsum;
    dst[(long long)wave * DIM + lane] = acc / d;
}

static void run_hop(const int* rows, const int* cols, const float* vals,
                    int nnz, int n_rows,
                    const float* src, float* dst,
                    int* row_off, int* counts, int* block_sums,
                    int* col_s, float* val_s, hipStream_t stream) {
    const int B = 256;
    int nblocks = (n_rows + B - 1) / B;

    hipMemsetAsync(counts, 0, (size_t)n_rows * sizeof(int), stream);
    hist_kernel<<<(nnz + B - 1) / B, B, 0, stream>>>(rows, nnz, counts);

    scan_blocks_kernel<<<nblocks, B, 0, stream>>>(counts, n_rows, row_off, block_sums);
    scan_sums_kernel<<<1, 512, 0, stream>>>(block_sums, nblocks);
    add_offsets_kernel<<<nblocks, B, 0, stream>>>(row_off, block_sums, n_rows);

    hipMemsetAsync(counts, 0, (size_t)n_rows * sizeof(int), stream);
    scatter_sorted_kernel<<<(nnz + B - 1) / B, B, 0, stream>>>(
        rows, cols, vals, row_off, counts, col_s, val_s, nnz);

    int waves_per_block = B / 64;
    int gblocks = (n_rows + waves_per_block - 1) / waves_per_block;
    gather_rows_kernel<<<gblocks, B, 0, stream>>>(col_s, val_s, row_off,
                                                  src, dst, n_rows, nnz);
}

extern "C" void kernel_launch(void* const* d_in, const int* in_sizes, int n_in,
                              void* d_out, int out_size, void* d_ws, size_t ws_size,
                              hipStream_t stream) {
    const float* item_emb = (const float*)d_in[1];
    const int*   hv_rows  = (const int*)d_in[2];
    const int*   hv_cols  = (const int*)d_in[3];
    const float* hv_vals  = (const float*)d_in[4];
    const int*   hu_rows  = (const int*)d_in[5];
    const int*   hu_cols  = (const int*)d_in[6];
    const float* hu_vals  = (const float*)d_in[7];

    const int nnz1 = in_sizes[2];
    const int nnz2 = in_sizes[5];
    const int n_b  = 50000;
    const int n_u  = out_size / DIM;

    float* out = (float*)d_out;

    // Workspace layout (all 4-byte aligned)
    char* p = (char*)d_ws;
    float* bf         = (float*)p; p += (size_t)n_b * DIM * sizeof(float); // 12.8 MB
    int*   row_off1   = (int*)p;   p += (size_t)n_b * sizeof(int);
    int*   row_off2   = (int*)p;   p += (size_t)n_u * sizeof(int);
    int*   counts     = (int*)p;   p += (size_t)n_u * sizeof(int);         // max(n_b,n_u)
    int*   block_sums = (int*)p;   p += 512 * sizeof(int);
    int*   col_s      = (int*)p;   p += (size_t)nnz1 * sizeof(int);        // reused hop2 (nnz equal)
    float* val_s      = (float*)p; p += (size_t)nnz1 * sizeof(float);

    // Hop 1: item_emb -> bf
    run_hop(hv_rows, hv_cols, hv_vals, nnz1, n_b, item_emb, bf,
            row_off1, counts, block_sums, col_s, val_s, stream);
    // Hop 2: bf -> out
    run_hop(hu_rows, hu_cols, hu_vals, nnz2, n_u, bf, out,
            row_off2, counts, block_sums, col_s, val_s, stream);
}

// Round 3
// 662.350 us; speedup vs baseline: 1.8000x; 1.2393x over previous
//
#include <hip/hip_runtime.h>

// Two-hop SpMM-mean. Round 3:
//  - scatter packs (col,val) into one int2 -> single 8B scattered store/edge
//    (halves random-write sector traffic vs two 4B stores to separate arrays)
//  - gather processes 4 edges per wave iteration; quarter-wave (16 lanes)
//    reads each edge's row as float4 (256B/edge), 4 loads in flight, no
//    per-edge shfl broadcast loop; cross-subgroup reduce once per row.

#define DIM 64

__global__ void hist_kernel(const int* __restrict__ rows, int nnz,
                            int* __restrict__ counts) {
    int i = blockIdx.x * blockDim.x + threadIdx.x;
    if (i < nnz) atomicAdd(&counts[rows[i]], 1);
}

__global__ void scan_blocks_kernel(const int* __restrict__ in, int n,
                                   int* __restrict__ out,
                                   int* __restrict__ block_sums) {
    __shared__ int s[256];
    int t = threadIdx.x;
    int i = blockIdx.x * 256 + t;
    int x = (i < n) ? in[i] : 0;
    s[t] = x;
    __syncthreads();
    for (int off = 1; off < 256; off <<= 1) {
        int v = (t >= off) ? s[t - off] : 0;
        __syncthreads();
        s[t] += v;
        __syncthreads();
    }
    if (i < n) out[i] = s[t] - x;          // exclusive
    if (t == 255) block_sums[blockIdx.x] = s[255];
}

__global__ void scan_sums_kernel(int* __restrict__ sums, int n) {
    __shared__ int s[512];
    int t = threadIdx.x;
    int x = (t < n) ? sums[t] : 0;
    s[t] = x;
    __syncthreads();
    for (int off = 1; off < 512; off <<= 1) {
        int v = (t >= off) ? s[t - off] : 0;
        __syncthreads();
        s[t] += v;
        __syncthreads();
    }
    if (t < n) sums[t] = s[t] - x;         // exclusive
}

__global__ void add_offsets_kernel(int* __restrict__ out,
                                   const int* __restrict__ sums, int n) {
    int i = blockIdx.x * 256 + threadIdx.x;
    if (i < n) out[i] += sums[blockIdx.x];
}

__global__ void scatter_sorted_kernel(const int* __restrict__ rows,
                                      const int* __restrict__ cols,
                                      const float* __restrict__ vals,
                                      const int* __restrict__ row_off,
                                      int* __restrict__ cursor,      // zeroed
                                      int2* __restrict__ colval,
                                      int nnz) {
    int i = blockIdx.x * blockDim.x + threadIdx.x;
    if (i >= nnz) return;
    int r = rows[i];
    int pos = row_off[r] + atomicAdd(&cursor[r], 1);
    colval[pos] = make_int2(cols[i], __float_as_int(vals[i]));
}

// One wave per row. lane = 16*sub + ld: sub in [0,4) = edge slot,
// ld in [0,16) = float4 chunk of the 64-dim row.
__global__ void gather_rows_kernel(const int2* __restrict__ colval,
                                   const int* __restrict__ row_off,
                                   const float* __restrict__ src,   // [n_src,64]
                                   float* __restrict__ dst,         // [n_rows,64]
                                   int n_rows, int nnz) {
    int wave = (blockIdx.x * blockDim.x + threadIdx.x) >> 6;
    int lane = threadIdx.x & 63;
    if (wave >= n_rows) return;
    int sub = lane >> 4;
    int ld  = lane & 15;
    int start = row_off[wave];
    int end   = (wave + 1 < n_rows) ? row_off[wave + 1] : nnz;

    float ax = 0.f, ay = 0.f, az = 0.f, aw = 0.f;
    float vsum = 0.0f;
    for (int i = start; i < end; i += 4) {
        int idx = i + sub;
        int c = 0; float v = 0.0f;
        if (idx < end) {
            int2 cv = colval[idx];
            c = cv.x;
            v = __int_as_float(cv.y);
        }
        const float4 x = *(const float4*)(src + (long long)c * DIM + ld * 4);
        ax += v * x.x; ay += v * x.y; az += v * x.z; aw += v * x.w;
        vsum += v;
    }
    // reduce across the 4 sub-groups
    #pragma unroll
    for (int off = 16; off <= 32; off <<= 1) {
        ax += __shfl_xor(ax, off);
        ay += __shfl_xor(ay, off);
        az += __shfl_xor(az, off);
        aw += __shfl_xor(aw, off);
        vsum += __shfl_xor(vsum, off);
    }
    float d = (vsum == 0.0f) ? 1.0f : vsum;
    if (sub == 0) {
        float inv = 1.0f / d;
        float4 o = make_float4(ax * inv, ay * inv, az * inv, aw * inv);
        *(float4*)(dst + (long long)wave * DIM + ld * 4) = o;
    }
}

static void run_hop(const int* rows, const int* cols, const float* vals,
                    int nnz, int n_rows,
                    const float* src, float* dst,
                    int* row_off, int* counts, int* block_sums,
                    int2* colval, hipStream_t stream) {
    const int B = 256;
    int nblocks = (n_rows + B - 1) / B;

    hipMemsetAsync(counts, 0, (size_t)n_rows * sizeof(int), stream);
    hist_kernel<<<(nnz + B - 1) / B, B, 0, stream>>>(rows, nnz, counts);

    scan_blocks_kernel<<<nblocks, B, 0, stream>>>(counts, n_rows, row_off, block_sums);
    scan_sums_kernel<<<1, 512, 0, stream>>>(block_sums, nblocks);
    add_offsets_kernel<<<nblocks, B, 0, stream>>>(row_off, block_sums, n_rows);

    hipMemsetAsync(counts, 0, (size_t)n_rows * sizeof(int), stream);
    scatter_sorted_kernel<<<(nnz + B - 1) / B, B, 0, stream>>>(
        rows, cols, vals, row_off, counts, colval, nnz);

    int waves_per_block = B / 64;
    int gblocks = (n_rows + waves_per_block - 1) / waves_per_block;
    gather_rows_kernel<<<gblocks, B, 0, stream>>>(colval, row_off,
                                                  src, dst, n_rows, nnz);
}

extern "C" void kernel_launch(void* const* d_in, const int* in_sizes, int n_in,
                              void* d_out, int out_size, void* d_ws, size_t ws_size,
                              hipStream_t stream) {
    const float* item_emb = (const float*)d_in[1];
    const int*   hv_rows  = (const int*)d_in[2];
    const int*   hv_cols  = (const int*)d_in[3];
    const float* hv_vals  = (const float*)d_in[4];
    const int*   hu_rows  = (const int*)d_in[5];
    const int*   hu_cols  = (const int*)d_in[6];
    const float* hu_vals  = (const float*)d_in[7];

    const int nnz1 = in_sizes[2];
    const int nnz2 = in_sizes[5];
    const int n_b  = 50000;
    const int n_u  = out_size / DIM;

    float* out = (float*)d_out;

    // Workspace layout (offsets stay 16B-aligned: all region sizes are
    // multiples of 16 for these problem dims)
    char* p = (char*)d_ws;
    float* bf         = (float*)p; p += (size_t)n_b * DIM * sizeof(float); // 12.8 MB
    int*   row_off1   = (int*)p;   p += (size_t)n_b * sizeof(int);
    int*   row_off2   = (int*)p;   p += (size_t)n_u * sizeof(int);
    int*   counts     = (int*)p;   p += (size_t)n_u * sizeof(int);         // max(n_b,n_u)
    int*   block_sums = (int*)p;   p += 512 * sizeof(int);
    int2*  colval     = (int2*)p;  p += (size_t)nnz1 * sizeof(int2);       // reused hop2

    // Hop 1: item_emb -> bf
    run_hop(hv_rows, hv_cols, hv_vals, nnz1, n_b, item_emb, bf,
            row_off1, counts, block_sums, colval, stream);
    // Hop 2: bf -> out
    run_hop(hu_rows, hu_cols, hu_vals, nnz2, n_u, bf, out,
            row_off2, counts, block_sums, colval, stream);
}